// Round 1
// baseline (1161.803 us; speedup 1.0000x reference)
//
#include <hip/hip_runtime.h>

typedef _Float16 h4 __attribute__((ext_vector_type(4)));
typedef _Float16 h8 __attribute__((ext_vector_type(8)));
typedef float    f4 __attribute__((ext_vector_type(4)));

#define D    64
#define LDSP 72   // padded LDS row stride in halves (144 B: breaks pow-2 bank aliasing, keeps 16B align)

__global__ __launch_bounds__(256)
void dist_mfma_kernel(const float* __restrict__ s, const float* __restrict__ t,
                      float* __restrict__ out, int n, int q)
{
    __shared__ __align__(16) _Float16 shS[128 * LDSP];
    __shared__ __align__(16) _Float16 shT[128 * LDSP];
    __shared__ float shSq[128];
    __shared__ float shTq[128];

    const int tid   = threadIdx.x;
    const int bi    = blockIdx.y;
    const int bj    = blockIdx.x;
    const int srow0 = bi * 128;
    const int trow0 = bj * 128;

    // ---- stage: fp32 global -> f16 LDS, fully coalesced (1 KiB/wave/instr) ----
    // per matrix: 128 rows x 16 float4 chunks = 2048 chunks; each thread does 8.
    #pragma unroll
    for (int i = 0; i < 8; ++i) {
        int c   = tid + 256 * i;
        int row = c >> 4;
        int c4  = c & 15;
        float4 v = reinterpret_cast<const float4*>(s + (size_t)(srow0 + row) * D)[c4];
        h4 hv = { (_Float16)v.x, (_Float16)v.y, (_Float16)v.z, (_Float16)v.w };
        *reinterpret_cast<h4*>(&shS[row * LDSP + c4 * 4]) = hv;
        float4 w = reinterpret_cast<const float4*>(t + (size_t)(trow0 + row) * D)[c4];
        h4 hw = { (_Float16)w.x, (_Float16)w.y, (_Float16)w.z, (_Float16)w.w };
        *reinterpret_cast<h4*>(&shT[row * LDSP + c4 * 4]) = hw;
    }
    __syncthreads();

    // ---- row squared-norms from the staged f16 (error correlates with cross term) ----
    {
        int row = tid & 127;
        const _Float16* src = (tid < 128) ? shS : shT;
        float a = 0.f;
        #pragma unroll
        for (int j = 0; j < 8; ++j) {
            h8 h = *reinterpret_cast<const h8*>(&src[row * LDSP + j * 8]);
            #pragma unroll
            for (int e = 0; e < 8; ++e) { float f = (float)h[e]; a = fmaf(f, f, a); }
        }
        if (tid < 128) shSq[row] = a; else shTq[row] = a;
    }
    // norm writes are made visible by the __syncthreads() after the MFMA loop.

    // ---- MFMA: wave computes 64x64 via 4x4 tiles of 16x16, K=64 in two steps ----
    const int lane = tid & 63;
    const int wave = tid >> 6;
    const int wm   = (wave >> 1) << 6;   // 0 or 64
    const int wn   = (wave & 1) << 6;    // 0 or 64
    const int fr   = lane & 15;          // fragment row (m for A, n for B)
    const int fko  = (lane >> 4) << 3;   // k offset: 0,8,16,24

    f4 acc[4][4] = {};

    #pragma unroll
    for (int kb = 0; kb < D; kb += 32) {
        h8 af[4], bf[4];
        #pragma unroll
        for (int mi = 0; mi < 4; ++mi)
            af[mi] = *reinterpret_cast<const h8*>(&shS[(wm + mi * 16 + fr) * LDSP + kb + fko]);
        #pragma unroll
        for (int ni = 0; ni < 4; ++ni)
            bf[ni] = *reinterpret_cast<const h8*>(&shT[(wn + ni * 16 + fr) * LDSP + kb + fko]);
        #pragma unroll
        for (int mi = 0; mi < 4; ++mi)
            #pragma unroll
            for (int ni = 0; ni < 4; ++ni)
                acc[mi][ni] = __builtin_amdgcn_mfma_f32_16x16x32_f16(af[mi], bf[ni], acc[mi][ni], 0, 0, 0);
    }

    __syncthreads();  // make shSq/shTq visible to all waves

    // ---- epilogue: dist = ssq + tsq - 2*cross ; C/D: col=lane&15, row=(lane>>4)*4+reg ----
    const int rb = (lane >> 4) << 2;
    #pragma unroll
    for (int mi = 0; mi < 4; ++mi) {
        #pragma unroll
        for (int ni = 0; ni < 4; ++ni) {
            int lr = wm + mi * 16 + rb;
            int lc = wn + ni * 16 + (lane & 15);
            float tq = shTq[lc];
            size_t g = (size_t)(srow0 + lr) * (size_t)q + (size_t)(trow0 + lc);
            #pragma unroll
            for (int r = 0; r < 4; ++r) {
                out[g + (size_t)r * q] = shSq[lr + r] + tq - 2.0f * acc[mi][ni][r];
            }
        }
    }
}

extern "C" void kernel_launch(void* const* d_in, const int* in_sizes, int n_in,
                              void* d_out, int out_size, void* d_ws, size_t ws_size,
                              hipStream_t stream) {
    const float* s = (const float*)d_in[0];
    const float* t = (const float*)d_in[1];
    float* out = (float*)d_out;
    int n = in_sizes[0] / D;   // 16384
    int q = in_sizes[1] / D;   // 16384
    dim3 grid(q / 128, n / 128);
    dist_mfma_kernel<<<grid, dim3(256), 0, stream>>>(s, t, out, n, q);
}